// Round 9
// baseline (681.740 us; speedup 1.0000x reference)
//
#include <hip/hip_runtime.h>
#include <math.h>

// B=1024, D=128, DH=64, H=512 ; rows = B*D = 131072
// Hc (f16): [1024, 8192], Hc[b, k*128+d] = h[b,d,k]

typedef __attribute__((ext_vector_type(8))) short bf16x8;      // raw 16B mover / bf16
typedef __attribute__((ext_vector_type(8))) _Float16 f16x8;
typedef __attribute__((ext_vector_type(4))) float f32x4;

static __device__ __forceinline__ unsigned short f2bf(float f) {
    unsigned u = __builtin_bit_cast(unsigned, f);
    unsigned r = (u + 0x7FFFu + ((u >> 16) & 1u)) >> 16;
    return (unsigned short)r;
}
static __device__ __forceinline__ unsigned pk_f16(float a, float b) {
    auto h = __builtin_amdgcn_cvt_pkrtz(a, b);   // __fp16 ext_vector_type(2)
    return __builtin_bit_cast(unsigned, h);
}

static __device__ __forceinline__ float fexp2(float x) {
#if __has_builtin(__builtin_amdgcn_exp2f)
    return __builtin_amdgcn_exp2f(x);
#else
    float r; asm("v_exp_f32 %0, %1" : "=v"(r) : "v"(x)); return r;
#endif
}
static __device__ __forceinline__ float frcp(float x) {
#if __has_builtin(__builtin_amdgcn_rcpf)
    return __builtin_amdgcn_rcpf(x);
#else
    float r; asm("v_rcp_f32 %0, %1" : "=v"(r) : "v"(x)); return r;
#endif
}
// tanh(x) = 1 - 2/(1+e^{2x}); exp2-based, ~1e-6 abs err, saturates correctly.
static __device__ __forceinline__ float fast_tanh(float x) {
    const float e = fexp2(x * 2.8853900817779268f);   // e^{2x}
    const float r = frcp(1.f + e);
    return __builtin_fmaf(-2.f, r, 1.f);
}

// ---------------------------------------------------------------------------
// Merged prep: blocks [0,256) W1f/W1s ; [256,384) W0t ; [384,896) W1t ;
//              [896,898) S1.
// W1f[j][k] = f16(W1d[k][j]) ; W1s[j][k] = f16(W0d[512+k] * W1d[k][j])
// W0t[n][k] = f16(W0d[2+k][n]) ; S1[j] = sum_k W0d[512+k]*W1d[k][j]
// W1t[n][k] (bf16, MADE-masked): see r5.
// ---------------------------------------------------------------------------
__global__ __launch_bounds__(256, 4)
void prep_k(const float* __restrict__ W1d, const float* __restrict__ W0d,
            const float* __restrict__ W1a, const float* __restrict__ W1b,
            _Float16* __restrict__ W1f, _Float16* __restrict__ W1s,
            _Float16* __restrict__ W0t, float* __restrict__ S1,
            unsigned short* __restrict__ W1t)
{
    __shared__ float tile[32][33];
    const int bidx = blockIdx.x;
    const int tid  = threadIdx.x;

    if (bidx < 256) {
        const int n0 = (bidx & 15) * 32, k0 = (bidx >> 4) * 32;
        const int c = tid & 31, r4 = tid >> 5;
        #pragma unroll
        for (int i = 0; i < 4; ++i) {
            const int r = r4 * 4 + i;
            tile[r][c] = W1d[(k0 + r) * 512 + n0 + c];
        }
        __syncthreads();
        #pragma unroll
        for (int i = 0; i < 4; ++i) {
            const int r = r4 * 4 + i;                 // output row (j)
            const float v   = tile[c][r];             // = W1d[k0+c][n0+r]
            const float w01 = W0d[512 + k0 + c];
            W1f[(n0 + r) * 512 + k0 + c] = (_Float16)v;
            W1s[(n0 + r) * 512 + k0 + c] = (_Float16)(w01 * v);
        }
    } else if (bidx < 384) {
        const int idx = (bidx - 256) * 256 + tid;     // 0..32767
        const int n = idx & 511, k = idx >> 9;
        W0t[n * 64 + k] = (_Float16)W0d[(2 + k) * 512 + n];
    } else if (bidx < 896) {
        const int rel = bidx - 384;                   // 0..511
        const int n0 = (rel & 31) * 32;               // 0..1023
        const int k0 = (rel >> 5) * 32;               // 0..511
        const float* __restrict__ src = (n0 < 512) ? W1a : W1b;
        const int nrel0 = n0 & 511;
        const int c = tid & 31, r4 = tid >> 5;
        #pragma unroll
        for (int i = 0; i < 4; ++i) {
            const int r = r4 * 4 + i;
            tile[r][c] = src[(k0 + r) * 512 + nrel0 + c];
        }
        __syncthreads();
        #pragma unroll
        for (int i = 0; i < 4; ++i) {
            const int r = r4 * 4 + i;
            const int n = n0 + r;
            const int k = k0 + c;
            const bool keep = (k % 127) <= ((n & 511) % 127);
            W1t[(size_t)n * 512 + k] = keep ? f2bf(tile[c][r]) : (unsigned short)0;
        }
    } else {
        const int j = (bidx - 896) * 256 + tid;       // 0..511
        float s = 0.f;
        #pragma unroll 8
        for (int k = 0; k < 512; ++k)
            s += W0d[512 + k] * W1d[k * 512 + j];
        S1[j] = s;
    }
}

// ---------------------------------------------------------------------------
// MADE layer 1, both nets: x[1024,128] @ (W0 .* mask1) -> h1cat bf16 [1024][1024]
// ---------------------------------------------------------------------------
__global__ __launch_bounds__(256, 4)
void made1_k(const float* __restrict__ x,
             const float* __restrict__ Wn1, const float* __restrict__ Wn2,
             const float* __restrict__ bn1, const float* __restrict__ bn2,
             unsigned short* __restrict__ h1cat)
{
    __shared__ float As[16][68];
    __shared__ float Bs[16][68];

    const int tid = threadIdx.x;
    const int bn  = blockIdx.x;          // 0..15 : net = bn>>3
    const int bm  = blockIdx.y;          // 0..15
    const int net = bn >> 3;
    const int nb  = (bn & 7) * 64;
    const int tx = tid & 15, ty = tid >> 4;
    const int m_base = bm * 64;

    const float* __restrict__ W  = net ? Wn2 : Wn1;
    const float* __restrict__ bi = net ? bn2 : bn1;

    float acc[4][4] = {};

    for (int k0 = 0; k0 < 128; k0 += 16) {
        {
            const int m  = tid >> 2;
            const int kk = (tid & 3) * 4;
            const float4 a4 = *reinterpret_cast<const float4*>(&x[(size_t)(m_base + m) * 128 + k0 + kk]);
            As[kk + 0][m] = a4.x; As[kk + 1][m] = a4.y;
            As[kk + 2][m] = a4.z; As[kk + 3][m] = a4.w;
        }
        {
            const int kk = tid >> 4;
            const int nn = (tid & 15) * 4;
            const int gk = k0 + kk;
            const int gn = nb + nn;
            float4 b4 = *reinterpret_cast<const float4*>(&W[gk * 512 + gn]);
            float bv[4] = {b4.x, b4.y, b4.z, b4.w};
            #pragma unroll
            for (int j = 0; j < 4; ++j) {
                const int n = gn + j;
                const bool keep = net ? ((127 - gk) <= (n % 127)) : (gk <= (n % 127));
                Bs[kk][nn + j] = keep ? bv[j] : 0.f;
            }
        }
        __syncthreads();
        #pragma unroll
        for (int kk = 0; kk < 16; ++kk) {
            const float4 a4 = *reinterpret_cast<const float4*>(&As[kk][ty * 4]);
            const float4 b4 = *reinterpret_cast<const float4*>(&Bs[kk][tx * 4]);
            const float av[4] = {a4.x, a4.y, a4.z, a4.w};
            const float bv[4] = {b4.x, b4.y, b4.z, b4.w};
            #pragma unroll
            for (int i = 0; i < 4; ++i)
                #pragma unroll
                for (int j = 0; j < 4; ++j)
                    acc[i][j] += av[i] * bv[j];
        }
        __syncthreads();
    }

    #pragma unroll
    for (int i = 0; i < 4; ++i) {
        const int m = m_base + ty * 4 + i;
        #pragma unroll
        for (int j = 0; j < 4; ++j) {
            const int n = nb + tx * 4 + j;
            const float v = fmaxf(acc[i][j] + bi[n], 0.f);
            h1cat[(size_t)m * 1024 + net * 512 + n] = f2bf(v);
        }
    }
}

// ---------------------------------------------------------------------------
// MADE W2 masked+transposed: W2t[n 0..8191][k 0..1023] bf16
// ---------------------------------------------------------------------------
__global__ __launch_bounds__(256, 4)
void prep_w2t_k(const float* __restrict__ W2a, const float* __restrict__ W2b,
                unsigned short* __restrict__ W2t)
{
    __shared__ float tile[32][33];
    const int tid = threadIdx.x;
    const int n0 = blockIdx.x * 32;      // 0..8191
    const int k0 = blockIdx.y * 32;      // 0..1023
    const float* __restrict__ src = (k0 < 512) ? W2a : W2b;
    const int krel0 = k0 & 511;
    const bool net1 = (k0 >= 512);
    const int c = tid & 31, r4 = tid >> 5;
    #pragma unroll
    for (int i = 0; i < 4; ++i) {
        const int r = r4 * 4 + i;        // k-offset
        tile[r][c] = src[(size_t)(krel0 + r) * 8192 + n0 + c];
    }
    __syncthreads();
    #pragma unroll
    for (int i = 0; i < 4; ++i) {
        const int r = r4 * 4 + i;        // n-offset
        const int n = n0 + r;
        const int k = k0 + c;
        const int km = (k & 511) % 127;
        const int dg = n & 127;
        const bool keep = net1 ? (km < 127 - dg) : (km < dg);
        W2t[(size_t)n * 1024 + k] = keep ? f2bf(tile[c][r]) : (unsigned short)0;
    }
}

// ---------------------------------------------------------------------------
// MADE layer 2: h2 = relu(h1 @ W1m + b). Barrier-free MFMA, tile 64x64.
// ---------------------------------------------------------------------------
__global__ __launch_bounds__(512, 2)
void gemm2_k(const unsigned short* __restrict__ h1cat,
             const unsigned short* __restrict__ W1t,
             const float* __restrict__ ba, const float* __restrict__ bb,
             unsigned short* __restrict__ h2cat)
{
    const int tid = threadIdx.x;
    const int n0 = blockIdx.x * 64;
    const int m0 = blockIdx.y * 64;
    const int lane = tid & 63, w = tid >> 6;
    const int l15 = lane & 15, l16 = lane >> 4;
    const int wm = w & 3, wn = w >> 2;
    const int net = n0 >> 9;
    const float* __restrict__ bi = net ? bb : ba;

    const unsigned short* Ab = h1cat + (size_t)(m0 + wm * 16 + l15) * 1024 + net * 512 + l16 * 8;
    const unsigned short* Bb = W1t + (size_t)(n0 + wn * 32 + l15) * 512 + l16 * 8;

    f32x4 acc[2] = {};
    bf16x8 a0, b0[2], a1, b1[2];
    a0 = *(const bf16x8*)(Ab);
    b0[0] = *(const bf16x8*)(Bb);
    b0[1] = *(const bf16x8*)(Bb + 16 * 512);

    #pragma unroll
    for (int s = 0; s < 15; ++s) {
        const int off = (s + 1) * 32;
        a1 = *(const bf16x8*)(Ab + off);
        b1[0] = *(const bf16x8*)(Bb + off);
        b1[1] = *(const bf16x8*)(Bb + 16 * 512 + off);
        acc[0] = __builtin_amdgcn_mfma_f32_16x16x32_bf16(a0, b0[0], acc[0], 0, 0, 0);
        acc[1] = __builtin_amdgcn_mfma_f32_16x16x32_bf16(a0, b0[1], acc[1], 0, 0, 0);
        a0 = a1; b0[0] = b1[0]; b0[1] = b1[1];
    }
    acc[0] = __builtin_amdgcn_mfma_f32_16x16x32_bf16(a0, b0[0], acc[0], 0, 0, 0);
    acc[1] = __builtin_amdgcn_mfma_f32_16x16x32_bf16(a0, b0[1], acc[1], 0, 0, 0);

    #pragma unroll
    for (int nt = 0; nt < 2; ++nt) {
        const int n = n0 + wn * 32 + nt * 16 + l15;
        const float bv = bi[n & 511];
        #pragma unroll
        for (int e = 0; e < 4; ++e) {
            const float v = fmaxf(acc[nt][e] + bv, 0.f);
            h2cat[(size_t)(m0 + wm * 16 + l16 * 4 + e) * 1024 + n] = f2bf(v);
        }
    }
}

// ---------------------------------------------------------------------------
// MADE layer 3, both nets fused over K=1024: Hc(f16) = h2cat @ W2t^T + bias
// ---------------------------------------------------------------------------
__global__ __launch_bounds__(512, 2)
void gemm3_k(const unsigned short* __restrict__ h2cat,
             const unsigned short* __restrict__ W2t,
             const float* __restrict__ ba, const float* __restrict__ bb,
             _Float16* __restrict__ Hc)
{
    const int tid = threadIdx.x;
    const int n0 = blockIdx.x * 128, m0 = blockIdx.y * 128;
    const int lane = tid & 63, w = tid >> 6;
    const int l15 = lane & 15, l16 = lane >> 4;
    const int wm = w & 3, wn = w >> 2;

    const unsigned short* Ab = h2cat + (size_t)(m0 + wm * 32 + l15) * 1024 + l16 * 8;
    const unsigned short* Bb = W2t + (size_t)(n0 + wn * 64 + l15) * 1024 + l16 * 8;

    f32x4 acc[2][4] = {};
    bf16x8 a0[2], b0[4], a1[2], b1[4];
    #pragma unroll
    for (int mt = 0; mt < 2; ++mt) a0[mt] = *(const bf16x8*)(Ab + mt * 16 * 1024);
    #pragma unroll
    for (int nt = 0; nt < 4; ++nt) b0[nt] = *(const bf16x8*)(Bb + nt * 16 * 1024);

    for (int s = 0; s < 32; ++s) {
        if (s < 31) {
            const int off = (s + 1) * 32;
            #pragma unroll
            for (int mt = 0; mt < 2; ++mt) a1[mt] = *(const bf16x8*)(Ab + mt * 16 * 1024 + off);
            #pragma unroll
            for (int nt = 0; nt < 4; ++nt) b1[nt] = *(const bf16x8*)(Bb + nt * 16 * 1024 + off);
        }
        #pragma unroll
        for (int mt = 0; mt < 2; ++mt)
            #pragma unroll
            for (int nt = 0; nt < 4; ++nt)
                acc[mt][nt] = __builtin_amdgcn_mfma_f32_16x16x32_bf16(a0[mt], b0[nt], acc[mt][nt], 0, 0, 0);
        #pragma unroll
        for (int mt = 0; mt < 2; ++mt) a0[mt] = a1[mt];
        #pragma unroll
        for (int nt = 0; nt < 4; ++nt) b0[nt] = b1[nt];
    }

    #pragma unroll
    for (int nt = 0; nt < 4; ++nt) {
        const int n = n0 + wn * 64 + nt * 16 + l15;
        const float bsum = ba[n] + bb[n];
        #pragma unroll
        for (int mt = 0; mt < 2; ++mt) {
            const int mrow = m0 + wm * 32 + mt * 16 + l16 * 4;
            #pragma unroll
            for (int e = 0; e < 4; ++e)
                Hc[(size_t)(mrow + e) * 8192 + n] = (_Float16)(acc[mt][nt][e] + bsum);
        }
    }
}

// ---------------------------------------------------------------------------
// Fused dimwise MLP + exact JVP. r9 (=r8 fixed): f16 pipeline; tangent path
// derived from z^2 in registers (tpre2 = S1 - z2 @ W1s) -> NO tA in LDS
// (39KB total), half the LDS reads of r5. Block = 32 rows x 512 threads
// (8 waves), r5 topology (wave owns 64 cols, full unroll, peeled tail).
// LDS: zA [0,34816) Hstage [34816,38912) xbuf [38912,39040)
// zA layout: byte(k, brow) = (k>>3)*272 + (brow&15)*16 + (k&7)*2
//            (+17408 for brow>=16)
// ---------------------------------------------------------------------------
__global__ __launch_bounds__(512, 4)
void dimwise_k(const _Float16* __restrict__ Hc,
               const float* __restrict__ x, const float* __restrict__ t,
               const _Float16* __restrict__ W1f, const _Float16* __restrict__ W1s,
               const _Float16* __restrict__ W0t, const float* __restrict__ S1,
               const float* __restrict__ W0, const float* __restrict__ b0,
               const float* __restrict__ b1,
               const float* __restrict__ W2, const float* __restrict__ b2,
               float* __restrict__ out)
{
    __shared__ __align__(16) char smem[39040];

    const int tid  = threadIdx.x;
    // bijective XCD swizzle: 4 d-blocks of one batch row share an XCD L2.
    const int bid  = (blockIdx.x & 7) * 512 + (blockIdx.x >> 3);
    const int row0 = bid * 32;
    const int b    = row0 >> 7;
    const int d0   = row0 & 127;

    const int lane = tid & 63;
    const int w    = tid >> 6;          // wave 0..7, owns n in [w*64, w*64+64)
    const int l15 = lane & 15, l16 = lane >> 4;

    // ---- phase 0: stage Hc tile [32 row][64 k] (XOR-swizzled) + x ----
    if (tid < 256) {
        const int k    = tid >> 2;            // 0..63
        const int part = tid & 3;             // d offset part*8
        const bf16x8 hv = *(const bf16x8*)((const unsigned short*)Hc
                                           + (size_t)b * 8192 + k * 128 + d0 + part * 8);
        #pragma unroll
        for (int j = 0; j < 8; ++j) {
            const int row = part * 8 + j;
            const int byte = 34816 + row * 128 + ((2 * k) ^ ((row & 7) << 4));
            *(unsigned short*)(smem + byte) = (unsigned short)hv[j];
        }
    }
    if (tid < 32) ((float*)(smem + 38912))[tid] = x[b * 128 + d0 + tid];
    __syncthreads();

    // ---- phase 1: z1pre via SWAPPED MFMA (A=W0t rows=n, B=H cols=brow) ----
    // output: col=l15 -> brow (within mt-tile), row=l16*4+e -> n (within nt)
    f32x4 zacc[2][4] = {};   // [mt][nt]
    #pragma unroll
    for (int ks = 0; ks < 2; ++ks) {
        f16x8 af[2];
        #pragma unroll
        for (int mt = 0; mt < 2; ++mt) {
            const int row = mt * 16 + l15;
            const int inner = (ks * 64 + l16 * 16) ^ ((l15 & 7) << 4);
            af[mt] = *(const f16x8*)(smem + 34816 + row * 128 + inner);
        }
        #pragma unroll
        for (int nt = 0; nt < 4; ++nt) {
            const int n = w * 64 + nt * 16 + l15;
            const f16x8 wf = *(const f16x8*)(W0t + n * 64 + ks * 32 + l16 * 8);
            #pragma unroll
            for (int mt = 0; mt < 2; ++mt)
                zacc[mt][nt] = __builtin_amdgcn_mfma_f32_16x16x32_f16(wf, af[mt], zacc[mt][nt], 0, 0, 0);
        }
    }
    {
        const float tv = t[0];
        const float* xb = (const float*)(smem + 38912);
        float xv[2];
        #pragma unroll
        for (int mt = 0; mt < 2; ++mt) xv[mt] = xb[mt * 16 + l15];
        #pragma unroll
        for (int nt = 0; nt < 4; ++nt) {
            const int nq = w * 64 + nt * 16 + l16 * 4;     // 4 consecutive n
            const float4 b04 = *(const float4*)&b0[nq];
            const float4 wr0 = *(const float4*)&W0[nq];
            const float4 wr1 = *(const float4*)&W0[512 + nq];
            const int kboff = (nq >> 3) * 272 + (nq & 7) * 2;
            #pragma unroll
            for (int mt = 0; mt < 2; ++mt) {
                float zq[4];
                #pragma unroll
                for (int e = 0; e < 4; ++e) {
                    const float be  = (e == 0) ? b04.x : (e == 1) ? b04.y : (e == 2) ? b04.z : b04.w;
                    const float w0e = (e == 0) ? wr0.x : (e == 1) ? wr0.y : (e == 2) ? wr0.z : wr0.w;
                    const float w1e = (e == 0) ? wr1.x : (e == 1) ? wr1.y : (e == 2) ? wr1.z : wr1.w;
                    const float pre = zacc[mt][nt][e] + be + tv * w0e + xv[mt] * w1e;
                    zq[e] = fast_tanh(pre);
                }
                const int off = mt * 17408 + kboff + l15 * 16;
                *(uint2*)(smem + off) = make_uint2(pk_f16(zq[0], zq[1]), pk_f16(zq[2], zq[3]));
            }
        }
    }
    __syncthreads();

    // ---- phase 2: dual GEMM — z-path (W1f) + z^2-path (W1s), f16 MFMA ----
    const char* __restrict__ Wfb = (const char*)W1f + (size_t)(w * 64 + l15) * 1024 + l16 * 16;
    const char* __restrict__ Wsb = (const char*)W1s + (size_t)(w * 64 + l15) * 1024 + l16 * 16;
    const int aoff0 = l15 * 16 + l16 * 272;

    f32x4 accp[2][4] = {};
    f32x4 acct[2][4] = {};

    f16x8 za0[2], za1[2];
    #pragma unroll
    for (int mt = 0; mt < 2; ++mt)
        za0[mt] = *(const f16x8*)(smem + mt * 17408 + aoff0);

    #pragma unroll
    for (int ks = 0; ks < 15; ++ks) {
        const int aoff = aoff0 + (ks + 1) * 1088;
        #pragma unroll
        for (int mt = 0; mt < 2; ++mt)
            za1[mt] = *(const f16x8*)(smem + mt * 17408 + aoff);
        f16x8 bw[4], bs[4];
        #pragma unroll
        for (int nt = 0; nt < 4; ++nt) {
            bw[nt] = *(const f16x8*)(Wfb + nt * 16384 + ks * 64);
            bs[nt] = *(const f16x8*)(Wsb + nt * 16384 + ks * 64);
        }
        f16x8 zsq[2];
        #pragma unroll
        for (int mt = 0; mt < 2; ++mt) zsq[mt] = za0[mt] * za0[mt];
        #pragma unroll
        for (int mt = 0; mt < 2; ++mt)
            #pragma unroll
            for (int nt = 0; nt < 4; ++nt) {
                accp[mt][nt] = __builtin_amdgcn_mfma_f32_16x16x32_f16(za0[mt], bw[nt], accp[mt][nt], 0, 0, 0);
                acct[mt][nt] = __builtin_amdgcn_mfma_f32_16x16x32_f16(zsq[mt], bs[nt], acct[mt][nt], 0, 0, 0);
            }
        #pragma unroll
        for (int mt = 0; mt < 2; ++mt) za0[mt] = za1[mt];
    }
    {   // peeled tail ks=15
        f16x8 bw[4], bs[4];
        #pragma unroll
        for (int nt = 0; nt < 4; ++nt) {
            bw[nt] = *(const f16x8*)(Wfb + nt * 16384 + 15 * 64);
            bs[nt] = *(const f16x8*)(Wsb + nt * 16384 + 15 * 64);
        }
        f16x8 zsq[2];
        #pragma unroll
        for (int mt = 0; mt < 2; ++mt) zsq[mt] = za0[mt] * za0[mt];
        #pragma unroll
        for (int mt = 0; mt < 2; ++mt)
            #pragma unroll
            for (int nt = 0; nt < 4; ++nt) {
                accp[mt][nt] = __builtin_amdgcn_mfma_f32_16x16x32_f16(za0[mt], bw[nt], accp[mt][nt], 0, 0, 0);
                acct[mt][nt] = __builtin_amdgcn_mfma_f32_16x16x32_f16(zsq[mt], bs[nt], acct[mt][nt], 0, 0, 0);
            }
    }

    // ---- phase 3: tanh/JVP epilogue + 512->1 dot ----
    float py[2][4] = {}, pj[2][4] = {};
    #pragma unroll
    for (int nt = 0; nt < 4; ++nt) {
        const int n = w * 64 + nt * 16 + l15;
        const float b1v = b1[n];
        const float w2v = W2[n];
        const float s1v = S1[n];
        #pragma unroll
        for (int mt = 0; mt < 2; ++mt)
            #pragma unroll
            for (int e = 0; e < 4; ++e) {
                const float z2  = fast_tanh(accp[mt][nt][e] + b1v);
                const float tp  = s1v - acct[mt][nt][e];      // tpre2
                const float dz2 = (1.f - z2 * z2) * tp;
                py[mt][e] += z2  * w2v;
                pj[mt][e] += dz2 * w2v;
            }
    }
    #pragma unroll
    for (int off = 1; off < 16; off <<= 1)
        #pragma unroll
        for (int mt = 0; mt < 2; ++mt)
            #pragma unroll
            for (int e = 0; e < 4; ++e) {
                py[mt][e] += __shfl_xor(py[mt][e], off);
                pj[mt][e] += __shfl_xor(pj[mt][e], off);
            }

    __syncthreads();
    float* part = (float*)smem;         // [8 w][2 mt][16 row][2]
    if (l15 == 0) {
        const int q = l16;
        #pragma unroll
        for (int mt = 0; mt < 2; ++mt)
            #pragma unroll
            for (int e = 0; e < 4; ++e) {
                const int idx = ((w * 2 + mt) * 16 + 4 * q + e) * 2;
                part[idx]     = py[mt][e];
                part[idx + 1] = pj[mt][e];
            }
    }
    __syncthreads();
    if (tid < 64) {
        const int mt = tid >> 5, row = (tid >> 1) & 15, wh = tid & 1;
        float s = 0.f;
        #pragma unroll
        for (int w8 = 0; w8 < 8; ++w8)
            s += part[((w8 * 2 + mt) * 16 + row) * 2 + wh];
        const int grow = row0 + mt * 16 + row;
        if (wh == 0) out[grow] = s + b2[0];
        else         out[131072 + grow] = s;
    }
}

// ---------------------------------------------------------------------------
extern "C" void kernel_launch(void* const* d_in, const int* in_sizes, int n_in,
                              void* d_out, int out_size, void* d_ws, size_t ws_size,
                              hipStream_t stream)
{
    (void)in_sizes; (void)n_in; (void)out_size; (void)ws_size;

    const float* t     = (const float*)d_in[0];
    const float* x     = (const float*)d_in[1];
    const float* m1_W0 = (const float*)d_in[2];
    const float* m1_b0 = (const float*)d_in[3];
    const float* m1_W1 = (const float*)d_in[4];
    const float* m1_b1 = (const float*)d_in[5];
    const float* m1_W2 = (const float*)d_in[6];
    const float* m1_b2 = (const float*)d_in[7];
    const float* m2_W0 = (const float*)d_in[8];
    const float* m2_b0 = (const float*)d_in[9];
    const float* m2_W1 = (const float*)d_in[10];
    const float* m2_b1 = (const float*)d_in[11];
    const float* m2_W2 = (const float*)d_in[12];
    const float* m2_b2 = (const float*)d_in[13];
    const float* d_W0  = (const float*)d_in[14];
    const float* d_b0  = (const float*)d_in[15];
    const float* d_W1  = (const float*)d_in[16];
    const float* d_b1  = (const float*)d_in[17];
    const float* d_W2  = (const float*)d_in[18];
    const float* d_b2  = (const float*)d_in[19];

    // ws layout (peak 0x2320000 = 36.8MB):
    // [0x0000000] W1f 512K ; [0x0080000] W1s 512K ; [0x0100000] W0t 64K
    // [0x0110000] S1 4K ; [0x0120000] h2cat 2M ; [0x0320000] Hc(f16) 16M
    // [0x1320000] W2t 16M  (h1cat 2M @0x1320000 and W1t 1M @0x1520000
    //                       overlay W2t region; dead before prep_w2t)
    char* base = (char*)d_ws;
    _Float16*       W1f   = (_Float16*)(base);
    _Float16*       W1s   = (_Float16*)(base + 0x80000);
    _Float16*       W0t   = (_Float16*)(base + 0x100000);
    float*          S1    = (float*)(base + 0x110000);
    unsigned short* h2cat = (unsigned short*)(base + 0x120000);
    _Float16*       Hc    = (_Float16*)(base + 0x320000);
    unsigned short* W2t   = (unsigned short*)(base + 0x1320000);
    unsigned short* h1cat = (unsigned short*)(base + 0x1320000);  // overlay
    unsigned short* W1t   = (unsigned short*)(base + 0x1520000);  // overlay

    prep_k<<<dim3(898), dim3(256), 0, stream>>>(d_W1, d_W0, m1_W1, m2_W1,
                                                W1f, W1s, W0t, S1, W1t);

    made1_k<<<dim3(16, 16), dim3(256), 0, stream>>>(x, m1_W0, m2_W0, m1_b0, m2_b0, h1cat);
    gemm2_k<<<dim3(16, 16), dim3(512), 0, stream>>>(h1cat, W1t, m1_b1, m2_b1, h2cat);

    prep_w2t_k<<<dim3(256, 32), dim3(256), 0, stream>>>(m1_W2, m2_W2, W2t);
    gemm3_k<<<dim3(64, 8), dim3(512), 0, stream>>>(h2cat, W2t, m1_b2, m2_b2, Hc);

    dimwise_k<<<dim3(4096), dim3(512), 0, stream>>>(Hc, x, t, W1f, W1s, W0t, S1,
                                                    d_W0, d_b0, d_b1, d_W2, d_b2,
                                                    (float*)d_out);
}

// Round 10
// 426.608 us; speedup vs baseline: 1.5980x; 1.5980x over previous
//
#include <hip/hip_runtime.h>
#include <math.h>

// B=1024, D=128, DH=64, H=512 ; rows = B*D = 131072
// Hc (bf16): [1024, 8192], Hc[b, k*128+d] = h[b,d,k]

typedef __attribute__((ext_vector_type(8))) short bf16x8;
typedef __attribute__((ext_vector_type(4))) float f32x4;
typedef __attribute__((ext_vector_type(16))) float f32x16;

static __device__ __forceinline__ unsigned short f2bf(float f) {
    unsigned u = __builtin_bit_cast(unsigned, f);
    unsigned r = (u + 0x7FFFu + ((u >> 16) & 1u)) >> 16;
    return (unsigned short)r;
}
static __device__ __forceinline__ unsigned cvt_pk_bf16(float lo, float hi) {
    unsigned r;
    asm("v_cvt_pk_bf16_f32 %0, %1, %2" : "=v"(r) : "v"(lo), "v"(hi));
    return r;
}

static __device__ __forceinline__ float fexp2(float x) {
#if __has_builtin(__builtin_amdgcn_exp2f)
    return __builtin_amdgcn_exp2f(x);
#else
    float r; asm("v_exp_f32 %0, %1" : "=v"(r) : "v"(x)); return r;
#endif
}
static __device__ __forceinline__ float frcp(float x) {
#if __has_builtin(__builtin_amdgcn_rcpf)
    return __builtin_amdgcn_rcpf(x);
#else
    float r; asm("v_rcp_f32 %0, %1" : "=v"(r) : "v"(x)); return r;
#endif
}
// tanh(x) = 1 - 2/(1+e^{2x}); exp2-based, ~1e-6 abs err, saturates correctly.
static __device__ __forceinline__ float fast_tanh(float x) {
    const float e = fexp2(x * 2.8853900817779268f);   // e^{2x}
    const float r = frcp(1.f + e);
    return __builtin_fmaf(-2.f, r, 1.f);
}

// ---------------------------------------------------------------------------
// MADE layer 1, both nets: x[1024,128] @ (W0 .* mask1) -> h1cat bf16 [1024][1024]
// ---------------------------------------------------------------------------
__global__ __launch_bounds__(256, 4)
void made1_k(const float* __restrict__ x,
             const float* __restrict__ Wn1, const float* __restrict__ Wn2,
             const float* __restrict__ bn1, const float* __restrict__ bn2,
             unsigned short* __restrict__ h1cat)
{
    __shared__ float As[16][68];
    __shared__ float Bs[16][68];

    const int tid = threadIdx.x;
    const int bn  = blockIdx.x;          // 0..15 : net = bn>>3
    const int bm  = blockIdx.y;          // 0..15
    const int net = bn >> 3;
    const int nb  = (bn & 7) * 64;
    const int tx = tid & 15, ty = tid >> 4;
    const int m_base = bm * 64;

    const float* __restrict__ W  = net ? Wn2 : Wn1;
    const float* __restrict__ bi = net ? bn2 : bn1;

    float acc[4][4] = {};

    for (int k0 = 0; k0 < 128; k0 += 16) {
        {
            const int m  = tid >> 2;
            const int kk = (tid & 3) * 4;
            const float4 a4 = *reinterpret_cast<const float4*>(&x[(size_t)(m_base + m) * 128 + k0 + kk]);
            As[kk + 0][m] = a4.x; As[kk + 1][m] = a4.y;
            As[kk + 2][m] = a4.z; As[kk + 3][m] = a4.w;
        }
        {
            const int kk = tid >> 4;
            const int nn = (tid & 15) * 4;
            const int gk = k0 + kk;
            const int gn = nb + nn;
            float4 b4 = *reinterpret_cast<const float4*>(&W[gk * 512 + gn]);
            float bv[4] = {b4.x, b4.y, b4.z, b4.w};
            #pragma unroll
            for (int j = 0; j < 4; ++j) {
                const int n = gn + j;
                const bool keep = net ? ((127 - gk) <= (n % 127)) : (gk <= (n % 127));
                Bs[kk][nn + j] = keep ? bv[j] : 0.f;
            }
        }
        __syncthreads();
        #pragma unroll
        for (int kk = 0; kk < 16; ++kk) {
            const float4 a4 = *reinterpret_cast<const float4*>(&As[kk][ty * 4]);
            const float4 b4 = *reinterpret_cast<const float4*>(&Bs[kk][tx * 4]);
            const float av[4] = {a4.x, a4.y, a4.z, a4.w};
            const float bv[4] = {b4.x, b4.y, b4.z, b4.w};
            #pragma unroll
            for (int i = 0; i < 4; ++i)
                #pragma unroll
                for (int j = 0; j < 4; ++j)
                    acc[i][j] += av[i] * bv[j];
        }
        __syncthreads();
    }

    #pragma unroll
    for (int i = 0; i < 4; ++i) {
        const int m = m_base + ty * 4 + i;
        #pragma unroll
        for (int j = 0; j < 4; ++j) {
            const int n = nb + tx * 4 + j;
            const float v = fmaxf(acc[i][j] + bi[n], 0.f);
            h1cat[(size_t)m * 1024 + net * 512 + n] = f2bf(v);
        }
    }
}

// ---------------------------------------------------------------------------
// W1 (dimwise) [512 k][512 n] f32 -> W1p [512 n][512 k] bf16 (unmasked)
// ---------------------------------------------------------------------------
__global__ __launch_bounds__(256, 4)
void prep_w1_k(const float* __restrict__ W1, unsigned short* __restrict__ W1p)
{
    __shared__ float tile[32][33];
    const int tid = threadIdx.x;
    const int k0 = blockIdx.y * 32, n0 = blockIdx.x * 32;
    const int c = tid & 31, r4 = tid >> 5;
    #pragma unroll
    for (int i = 0; i < 4; ++i) {
        const int r = r4 * 4 + i;
        tile[r][c] = W1[(k0 + r) * 512 + n0 + c];
    }
    __syncthreads();
    #pragma unroll
    for (int i = 0; i < 4; ++i) {
        const int r = r4 * 4 + i;
        W1p[(n0 + r) * 512 + k0 + c] = f2bf(tile[c][r]);
    }
}

// ---------------------------------------------------------------------------
// W0 (dimwise) h-rows -> W0t[512 n][64 k] bf16 (W0t[n][k] = W0[2+k][n])
// ---------------------------------------------------------------------------
__global__ __launch_bounds__(256, 4)
void prep_w0t_k(const float* __restrict__ W0, unsigned short* __restrict__ W0t)
{
    const int idx = blockIdx.x * 256 + threadIdx.x;   // 0..32767
    const int n = idx & 511, k = idx >> 9;
    W0t[n * 64 + k] = f2bf(W0[(2 + k) * 512 + n]);
}

// ---------------------------------------------------------------------------
// MADE W1 masked+transposed: W1t[n 0..1023][k 0..511] bf16
// ---------------------------------------------------------------------------
__global__ __launch_bounds__(256, 4)
void prep_w1t_k(const float* __restrict__ W1a, const float* __restrict__ W1b,
                unsigned short* __restrict__ W1t)
{
    __shared__ float tile[32][33];
    const int tid = threadIdx.x;
    const int n0 = blockIdx.x * 32;      // 0..1023
    const int k0 = blockIdx.y * 32;      // 0..511
    const float* __restrict__ src = (n0 < 512) ? W1a : W1b;
    const int nrel0 = n0 & 511;
    const int c = tid & 31, r4 = tid >> 5;
    #pragma unroll
    for (int i = 0; i < 4; ++i) {
        const int r = r4 * 4 + i;        // k-offset
        tile[r][c] = src[(k0 + r) * 512 + nrel0 + c];
    }
    __syncthreads();
    #pragma unroll
    for (int i = 0; i < 4; ++i) {
        const int r = r4 * 4 + i;        // n-offset
        const int n = n0 + r;
        const int k = k0 + c;
        const bool keep = (k % 127) <= ((n & 511) % 127);
        W1t[(size_t)n * 512 + k] = keep ? f2bf(tile[c][r]) : (unsigned short)0;
    }
}

// ---------------------------------------------------------------------------
// MADE W2 masked+transposed: W2t[n 0..8191][k 0..1023] bf16
// ---------------------------------------------------------------------------
__global__ __launch_bounds__(256, 4)
void prep_w2t_k(const float* __restrict__ W2a, const float* __restrict__ W2b,
                unsigned short* __restrict__ W2t)
{
    __shared__ float tile[32][33];
    const int tid = threadIdx.x;
    const int n0 = blockIdx.x * 32;      // 0..8191
    const int k0 = blockIdx.y * 32;      // 0..1023
    const float* __restrict__ src = (k0 < 512) ? W2a : W2b;
    const int krel0 = k0 & 511;
    const bool net1 = (k0 >= 512);
    const int c = tid & 31, r4 = tid >> 5;
    #pragma unroll
    for (int i = 0; i < 4; ++i) {
        const int r = r4 * 4 + i;        // k-offset
        tile[r][c] = src[(size_t)(krel0 + r) * 8192 + n0 + c];
    }
    __syncthreads();
    #pragma unroll
    for (int i = 0; i < 4; ++i) {
        const int r = r4 * 4 + i;        // n-offset
        const int n = n0 + r;
        const int k = k0 + c;
        const int km = (k & 511) % 127;
        const int dg = n & 127;
        const bool keep = net1 ? (km < 127 - dg) : (km < dg);
        W2t[(size_t)n * 1024 + k] = keep ? f2bf(tile[c][r]) : (unsigned short)0;
    }
}

// ---------------------------------------------------------------------------
// MADE layer 2: h2 = relu(h1 @ W1m + b). Barrier-free MFMA, tile 64x64.
// ---------------------------------------------------------------------------
__global__ __launch_bounds__(512, 2)
void gemm2_k(const unsigned short* __restrict__ h1cat,
             const unsigned short* __restrict__ W1t,
             const float* __restrict__ ba, const float* __restrict__ bb,
             unsigned short* __restrict__ h2cat)
{
    const int tid = threadIdx.x;
    const int n0 = blockIdx.x * 64;
    const int m0 = blockIdx.y * 64;
    const int lane = tid & 63, w = tid >> 6;
    const int l15 = lane & 15, l16 = lane >> 4;
    const int wm = w & 3, wn = w >> 2;
    const int net = n0 >> 9;
    const float* __restrict__ bi = net ? bb : ba;

    const unsigned short* Ab = h1cat + (size_t)(m0 + wm * 16 + l15) * 1024 + net * 512 + l16 * 8;
    const unsigned short* Bb = W1t + (size_t)(n0 + wn * 32 + l15) * 512 + l16 * 8;

    f32x4 acc[2] = {};
    bf16x8 a0, b0[2], a1, b1[2];
    a0 = *(const bf16x8*)(Ab);
    b0[0] = *(const bf16x8*)(Bb);
    b0[1] = *(const bf16x8*)(Bb + 16 * 512);

    #pragma unroll
    for (int s = 0; s < 15; ++s) {
        const int off = (s + 1) * 32;
        a1 = *(const bf16x8*)(Ab + off);
        b1[0] = *(const bf16x8*)(Bb + off);
        b1[1] = *(const bf16x8*)(Bb + 16 * 512 + off);
        acc[0] = __builtin_amdgcn_mfma_f32_16x16x32_bf16(a0, b0[0], acc[0], 0, 0, 0);
        acc[1] = __builtin_amdgcn_mfma_f32_16x16x32_bf16(a0, b0[1], acc[1], 0, 0, 0);
        a0 = a1; b0[0] = b1[0]; b0[1] = b1[1];
    }
    acc[0] = __builtin_amdgcn_mfma_f32_16x16x32_bf16(a0, b0[0], acc[0], 0, 0, 0);
    acc[1] = __builtin_amdgcn_mfma_f32_16x16x32_bf16(a0, b0[1], acc[1], 0, 0, 0);

    #pragma unroll
    for (int nt = 0; nt < 2; ++nt) {
        const int n = n0 + wn * 32 + nt * 16 + l15;
        const float bv = bi[n & 511];
        #pragma unroll
        for (int e = 0; e < 4; ++e) {
            const float v = fmaxf(acc[nt][e] + bv, 0.f);
            h2cat[(size_t)(m0 + wm * 16 + l16 * 4 + e) * 1024 + n] = f2bf(v);
        }
    }
}

// ---------------------------------------------------------------------------
// MADE layer 3, both nets fused over K=1024: Hc = h2cat @ W2t^T + (b2a+b2b)
// ---------------------------------------------------------------------------
__global__ __launch_bounds__(512, 2)
void gemm3_k(const unsigned short* __restrict__ h2cat,
             const unsigned short* __restrict__ W2t,
             const float* __restrict__ ba, const float* __restrict__ bb,
             unsigned short* __restrict__ Hc)
{
    const int tid = threadIdx.x;
    const int n0 = blockIdx.x * 128, m0 = blockIdx.y * 128;
    const int lane = tid & 63, w = tid >> 6;
    const int l15 = lane & 15, l16 = lane >> 4;
    const int wm = w & 3, wn = w >> 2;

    const unsigned short* Ab = h2cat + (size_t)(m0 + wm * 32 + l15) * 1024 + l16 * 8;
    const unsigned short* Bb = W2t + (size_t)(n0 + wn * 64 + l15) * 1024 + l16 * 8;

    f32x4 acc[2][4] = {};
    bf16x8 a0[2], b0[4], a1[2], b1[4];
    #pragma unroll
    for (int mt = 0; mt < 2; ++mt) a0[mt] = *(const bf16x8*)(Ab + mt * 16 * 1024);
    #pragma unroll
    for (int nt = 0; nt < 4; ++nt) b0[nt] = *(const bf16x8*)(Bb + nt * 16 * 1024);

    for (int s = 0; s < 32; ++s) {
        if (s < 31) {
            const int off = (s + 1) * 32;
            #pragma unroll
            for (int mt = 0; mt < 2; ++mt) a1[mt] = *(const bf16x8*)(Ab + mt * 16 * 1024 + off);
            #pragma unroll
            for (int nt = 0; nt < 4; ++nt) b1[nt] = *(const bf16x8*)(Bb + nt * 16 * 1024 + off);
        }
        #pragma unroll
        for (int mt = 0; mt < 2; ++mt)
            #pragma unroll
            for (int nt = 0; nt < 4; ++nt)
                acc[mt][nt] = __builtin_amdgcn_mfma_f32_16x16x32_bf16(a0[mt], b0[nt], acc[mt][nt], 0, 0, 0);
        #pragma unroll
        for (int mt = 0; mt < 2; ++mt) a0[mt] = a1[mt];
        #pragma unroll
        for (int nt = 0; nt < 4; ++nt) b0[nt] = b1[nt];
    }

    #pragma unroll
    for (int nt = 0; nt < 4; ++nt) {
        const int n = n0 + wn * 64 + nt * 16 + l15;
        const float bsum = ba[n] + bb[n];
        #pragma unroll
        for (int mt = 0; mt < 2; ++mt) {
            const int mrow = m0 + wm * 32 + mt * 16 + l16 * 4;
            #pragma unroll
            for (int e = 0; e < 4; ++e)
                Hc[(size_t)(mrow + e) * 8192 + n] = f2bf(acc[mt][nt][e] + bsum);
        }
    }
}

// ---------------------------------------------------------------------------
// Fused dimwise MLP + exact JVP. r10: phases 0/1 = verified r6 bf16 code;
// phase 2/3 rewritten on mfma_f32_32x32x16_bf16 — one 32x32 tile per path
// per wave (32 AGPR, half of r5) over 2 sequential 32-col groups with fused
// epilogue. Shared B-frag serves both paths; dist-2 B prefetch.
// LDS: zA [0,34816) tA [34816,69632) Hstage [69632,73728) xbuf [73728,73856)
// zA/tA layout: byte(k, brow) = (k>>3)*272 + (brow&15)*16 + (k&7)*2
//               (+17408 for brow>=16; tA at +34816)
// 32x32 C/D mapping: col=lane&31 (=n), row=(reg&3)+8*(reg>>2)+4*(lane>>5).
// ---------------------------------------------------------------------------
__global__ __launch_bounds__(512, 4)
void dimwise_k(const unsigned short* __restrict__ Hc,
               const float* __restrict__ x, const float* __restrict__ t,
               const unsigned short* __restrict__ W1p, const unsigned short* __restrict__ W0t,
               const float* __restrict__ W0, const float* __restrict__ b0,
               const float* __restrict__ b1,
               const float* __restrict__ W2, const float* __restrict__ b2,
               float* __restrict__ out)
{
    __shared__ __align__(16) char smem[73856];

    const int tid  = threadIdx.x;
    // bijective XCD swizzle: 4 d-blocks of one batch row share an XCD L2.
    const int bid  = (blockIdx.x & 7) * 512 + (blockIdx.x >> 3);
    const int row0 = bid * 32;
    const int b    = row0 >> 7;
    const int d0   = row0 & 127;

    const int lane = tid & 63;
    const int w    = tid >> 6;          // wave 0..7, owns n in [w*64, w*64+64)
    const int l15 = lane & 15, l16 = lane >> 4;
    const int l31 = lane & 31, l32 = lane >> 5;

    // ---- phase 0: stage Hc tile [32 row][64 k] (XOR-swizzled) + x ----
    if (tid < 256) {
        const int k    = tid >> 2;            // 0..63
        const int part = tid & 3;             // d offset part*8
        const bf16x8 hv = *(const bf16x8*)(Hc + (size_t)b * 8192 + k * 128 + d0 + part * 8);
        #pragma unroll
        for (int j = 0; j < 8; ++j) {
            const int row = part * 8 + j;
            const int byte = 69632 + row * 128 + ((2 * k) ^ ((row & 7) << 4));
            *(unsigned short*)(smem + byte) = (unsigned short)hv[j];
        }
    }
    if (tid < 32) ((float*)(smem + 73728))[tid] = x[b * 128 + d0 + tid];
    __syncthreads();

    // ---- phase 1: z1pre via SWAPPED MFMA (A=W0t rows=n, B=H cols=brow) ----
    // output: col=l15 -> brow (within mt-tile), row=l16*4+e -> n (within nt)
    f32x4 zacc[2][4] = {};   // [mt][nt]
    #pragma unroll
    for (int ks = 0; ks < 2; ++ks) {
        bf16x8 af[2];
        #pragma unroll
        for (int mt = 0; mt < 2; ++mt) {
            const int row = mt * 16 + l15;
            const int inner = (ks * 64 + l16 * 16) ^ ((l15 & 7) << 4);
            af[mt] = *(const bf16x8*)(smem + 69632 + row * 128 + inner);
        }
        #pragma unroll
        for (int nt = 0; nt < 4; ++nt) {
            const int n = w * 64 + nt * 16 + l15;
            const bf16x8 wf = *(const bf16x8*)(W0t + n * 64 + ks * 32 + l16 * 8);
            #pragma unroll
            for (int mt = 0; mt < 2; ++mt)
                zacc[mt][nt] = __builtin_amdgcn_mfma_f32_16x16x32_bf16(wf, af[mt], zacc[mt][nt], 0, 0, 0);
        }
    }
    {
        const float tv = t[0];
        const float* xb = (const float*)(smem + 73728);
        float xv[2];
        #pragma unroll
        for (int mt = 0; mt < 2; ++mt) xv[mt] = xb[mt * 16 + l15];
        #pragma unroll
        for (int nt = 0; nt < 4; ++nt) {
            const int nq = w * 64 + nt * 16 + l16 * 4;     // 4 consecutive n
            const float4 b04 = *(const float4*)&b0[nq];
            const float4 wr0 = *(const float4*)&W0[nq];
            const float4 wr1 = *(const float4*)&W0[512 + nq];
            const int kboff = (nq >> 3) * 272 + (nq & 7) * 2;
            #pragma unroll
            for (int mt = 0; mt < 2; ++mt) {
                float zq[4], sq[4];
                #pragma unroll
                for (int e = 0; e < 4; ++e) {
                    const float be  = (e == 0) ? b04.x : (e == 1) ? b04.y : (e == 2) ? b04.z : b04.w;
                    const float w0e = (e == 0) ? wr0.x : (e == 1) ? wr0.y : (e == 2) ? wr0.z : wr0.w;
                    const float w1e = (e == 0) ? wr1.x : (e == 1) ? wr1.y : (e == 2) ? wr1.z : wr1.w;
                    const float pre = zacc[mt][nt][e] + be + tv * w0e + xv[mt] * w1e;
                    const float z = fast_tanh(pre);
                    zq[e] = z;
                    sq[e] = (1.f - z * z) * w1e;
                }
                const int off = mt * 17408 + kboff + l15 * 16;
                *(uint2*)(smem + off)         = make_uint2(cvt_pk_bf16(zq[0], zq[1]), cvt_pk_bf16(zq[2], zq[3]));
                *(uint2*)(smem + 34816 + off) = make_uint2(cvt_pk_bf16(sq[0], sq[1]), cvt_pk_bf16(sq[2], sq[3]));
            }
        }
    }
    __syncthreads();

    // ---- phase 2+3: 32x32x16 dual-path GEMM per 32-col group + epilogue ----
    // A-frag (za/ta): row=l31, k=ks*16+l32*8 -> byte (ks*2+l32)*272 +
    //                 (l31&15)*16 + (l31>=16)*17408
    const int abase = (l31 & 15) * 16 + (l31 >> 4) * 17408 + l32 * 272;

    float py[16], pj[16];
    #pragma unroll
    for (int r = 0; r < 16; ++r) { py[r] = 0.f; pj[r] = 0.f; }

    #pragma unroll
    for (int g = 0; g < 2; ++g) {
        const int n = w * 64 + g * 32 + l31;
        const float b1v = b1[n];
        const float w2v = W2[n];
        const unsigned short* __restrict__ Wb = W1p + (size_t)n * 512 + l32 * 8;

        f32x16 accp = {}, acct = {};

        bf16x8 bw0 = *(const bf16x8*)(Wb);
        bf16x8 bw1 = *(const bf16x8*)(Wb + 16);

        #pragma unroll
        for (int ks = 0; ks < 32; ++ks) {
            bf16x8 bwn;
            if (ks + 2 < 32) bwn = *(const bf16x8*)(Wb + (ks + 2) * 16);
            const int ao = abase + ks * 544;
            const bf16x8 za = *(const bf16x8*)(smem + ao);
            const bf16x8 ta = *(const bf16x8*)(smem + 34816 + ao);
            accp = __builtin_amdgcn_mfma_f32_32x32x16_bf16(za, bw0, accp, 0, 0, 0);
            acct = __builtin_amdgcn_mfma_f32_32x32x16_bf16(ta, bw0, acct, 0, 0, 0);
            bw0 = bw1; bw1 = bwn;
        }

        #pragma unroll
        for (int r = 0; r < 16; ++r) {
            const float z2  = fast_tanh(accp[r] + b1v);
            const float dz2 = (1.f - z2 * z2) * acct[r];
            py[r] += z2  * w2v;
            pj[r] += dz2 * w2v;
        }
    }

    // reduce over the 32 cols of each half-wave (rows differ between halves)
    #pragma unroll
    for (int off = 1; off < 32; off <<= 1)
        #pragma unroll
        for (int r = 0; r < 16; ++r) {
            py[r] += __shfl_xor(py[r], off);
            pj[r] += __shfl_xor(pj[r], off);
        }

    __syncthreads();
    float* part = (float*)smem;         // [8 w][32 row][2]
    if (l31 == 0) {
        const int half = l32;
        #pragma unroll
        for (int r = 0; r < 16; ++r) {
            const int row = (r & 3) + 8 * (r >> 2) + 4 * half;
            part[(w * 32 + row) * 2 + 0] = py[r];
            part[(w * 32 + row) * 2 + 1] = pj[r];
        }
    }
    __syncthreads();
    if (tid < 64) {
        const int row = tid >> 1, wh = tid & 1;
        float s = 0.f;
        #pragma unroll
        for (int w8 = 0; w8 < 8; ++w8)
            s += part[(w8 * 32 + row) * 2 + wh];
        const int grow = row0 + row;
        if (wh == 0) out[grow] = s + b2[0];
        else         out[131072 + grow] = s;
    }
}

// ---------------------------------------------------------------------------
extern "C" void kernel_launch(void* const* d_in, const int* in_sizes, int n_in,
                              void* d_out, int out_size, void* d_ws, size_t ws_size,
                              hipStream_t stream)
{
    (void)in_sizes; (void)n_in; (void)out_size; (void)ws_size;

    const float* t     = (const float*)d_in[0];
    const float* x     = (const float*)d_in[1];
    const float* m1_W0 = (const float*)d_in[2];
    const float* m1_b0 = (const float*)d_in[3];
    const float* m1_W1 = (const float*)d_in[4];
    const float* m1_b1 = (const float*)d_in[5];
    const float* m1_W2 = (const float*)d_in[6];
    const float* m1_b2 = (const float*)d_in[7];
    const float* m2_W0 = (const float*)d_in[8];
    const float* m2_b0 = (const float*)d_in[9];
    const float* m2_W1 = (const float*)d_in[10];
    const float* m2_b1 = (const float*)d_in[11];
    const float* m2_W2 = (const float*)d_in[12];
    const float* m2_b2 = (const float*)d_in[13];
    const float* d_W0  = (const float*)d_in[14];
    const float* d_b0  = (const float*)d_in[15];
    const float* d_W1  = (const float*)d_in[16];
    const float* d_b1  = (const float*)d_in[17];
    const float* d_W2  = (const float*)d_in[18];
    const float* d_b2  = (const float*)d_in[19];

    // ws layout (peak 36.25 MB):
    // [0x0000000] W1p   512K ; [0x0080000] W0t 64K ; [0x0090000] h2cat 2M
    // [0x0290000] Hc 16M ; [0x1290000] W2t 16M (h1cat/W1t overlay W2t region)
    char* base = (char*)d_ws;
    unsigned short* W1p   = (unsigned short*)(base);
    unsigned short* W0t   = (unsigned short*)(base + 0x80000);
    unsigned short* h2cat = (unsigned short*)(base + 0x90000);
    unsigned short* Hc    = (unsigned short*)(base + 0x290000);
    unsigned short* W2t   = (unsigned short*)(base + 0x1290000);
    unsigned short* h1cat = (unsigned short*)(base + 0x1290000);  // overlay
    unsigned short* W1t   = (unsigned short*)(base + 0x1490000);  // overlay

    prep_w1_k<<<dim3(16, 16), dim3(256), 0, stream>>>(d_W1, W1p);
    prep_w0t_k<<<dim3(128), dim3(256), 0, stream>>>(d_W0, W0t);
    prep_w1t_k<<<dim3(32, 16), dim3(256), 0, stream>>>(m1_W1, m2_W1, W1t);

    made1_k<<<dim3(16, 16), dim3(256), 0, stream>>>(x, m1_W0, m2_W0, m1_b0, m2_b0, h1cat);
    gemm2_k<<<dim3(16, 16), dim3(512), 0, stream>>>(h1cat, W1t, m1_b1, m2_b1, h2cat);

    prep_w2t_k<<<dim3(256, 32), dim3(256), 0, stream>>>(m1_W2, m2_W2, W2t);
    gemm3_k<<<dim3(64, 8), dim3(512), 0, stream>>>(h2cat, W2t, m1_b2, m2_b2, Hc);

    dimwise_k<<<dim3(4096), dim3(512), 0, stream>>>(Hc, x, t, W1p, W0t,
                                                    d_W0, d_b0, d_b1, d_W2, d_b2,
                                                    (float*)d_out);
}